// Round 3
// baseline (30.584 us; speedup 1.0000x reference)
//
#include <hip/hip_runtime.h>

#define NBINS 256
#define NCH 3
#define BLOCK 512
#define HSIZE (NCH * NBINS)   // 768

__global__ __launch_bounds__(BLOCK, 8) void hist_kernel(const float* __restrict__ in,
                                                        float* __restrict__ out,
                                                        int blocksPerBatch,
                                                        int floatsPerBatch,
                                                        float inv_n) {
    __shared__ unsigned int h[HSIZE];   // 3 KB, single copy

    const int tid = threadIdx.x;
    for (int i = tid; i < HSIZE; i += BLOCK) h[i] = 0u;
    __syncthreads();

    const int b     = blockIdx.x / blocksPerBatch;
    const int chunk = blockIdx.x % blocksPerBatch;
    const int chunkFloats = floatsPerBatch / blocksPerBatch;           // 24576
    const size_t baseElem = (size_t)b * floatsPerBatch + (size_t)chunk * chunkFloats;
    const float4* p = (const float4*)(in + baseElem) + tid;            // lane-contiguous

    // channel of this thread's first element: (baseElem + tid*4) % 3
    int m0 = (int)((baseElem + (size_t)tid * 4) % 3);

    const int iters = chunkFloats / (BLOCK * 4);                       // 12

#pragma unroll 4
    for (int it = 0; it < iters; ++it) {
        float4 v = p[(size_t)it * BLOCK];   // coalesced: 64 lanes x contiguous 16B
        int c1 = m0 + 1; c1 = (c1 == 3) ? 0 : c1;
        int c2 = c1 + 1; c2 = (c2 == 3) ? 0 : c2;
        float vv[4] = {v.x, v.y, v.z, v.w};
        int   cc[4] = {m0, c1, c2, m0};     // channels of the 4 lanes' elements
#pragma unroll
        for (int j = 0; j < 4; ++j) {
            int bin = (int)(vv[j] * 256.0f);            // exact: mul by 2^8
            bin = bin < 0 ? 0 : (bin > NBINS - 1 ? NBINS - 1 : bin);
            atomicAdd(&h[(cc[j] << 8) + bin], 1u);
        }
        // stride per iter = 2048 floats, 2048 % 3 == 2 -> m0 = (m0 + 2) % 3
        m0 = (m0 == 0) ? 2 : m0 - 1;
    }
    __syncthreads();

    // scale exactly by 2^-18 and accumulate into transposed out[b][bin][c].
    // Addends are multiples of 2^-18, partial sums <= 1.0 -> float atomicAdd exact.
    float* dst = out + (size_t)b * HSIZE;
    for (int i = tid; i < HSIZE; i += BLOCK) {
        unsigned int s = h[i];
        if (s) {
            const int c   = i >> 8;
            const int bin = i & (NBINS - 1);
            atomicAdd(&dst[bin * NCH + c], (float)s * inv_n);
        }
    }
}

extern "C" void kernel_launch(void* const* d_in, const int* in_sizes, int n_in,
                              void* d_out, int out_size, void* d_ws, size_t ws_size,
                              hipStream_t stream) {
    const float* in = (const float*)d_in[0];
    float* out = (float*)d_out;

    const int floatsPerBatch = 512 * 512 * 3;        // H*W*C
    const int total = in_sizes[0];
    const int B = total / floatsPerBatch;            // 32
    const float inv_n = 1.0f / (float)(512 * 512);   // 2^-18, exact

    hipMemsetAsync(d_out, 0, (size_t)out_size * sizeof(float), stream);

    const int blocksPerBatch = 32;                   // 1024 blocks x 512 thr, 12 iters
    hist_kernel<<<B * blocksPerBatch, BLOCK, 0, stream>>>(in, out, blocksPerBatch,
                                                          floatsPerBatch, inv_n);
}